// Round 6
// baseline (1238.390 us; speedup 1.0000x reference)
//
#include <hip/hip_runtime.h>
#include <hip/hip_cooperative_groups.h>

namespace cg = cooperative_groups;

#define N_NODE 2048
#define D_DIM 64
#define ND ((size_t)N_NODE * (size_t)D_DIM)   // 131072 floats per (b,l) frame
#define L_SEQ 12

using s16x8 = __attribute__((ext_vector_type(8))) short;
using s16x4 = __attribute__((ext_vector_type(4))) short;
using f32x4 = __attribute__((ext_vector_type(4))) float;

__device__ __forceinline__ float relu_f(float x) { return fmaxf(x, 0.f); }

// f32 -> bf16 bits, round-to-nearest-even (finite data only)
__device__ __forceinline__ unsigned short f2bf(float f) {
    unsigned u = __float_as_uint(f);
    return (unsigned short)((u + 0x7FFFu + ((u >> 16) & 1u)) >> 16);
}

// LDS tile layout for 128x32 bf16 tiles: [row][32 k], 16B slot XOR-swizzle.
__device__ __forceinline__ int swz_off(int row, int slot) {
    return row * 32 + ((slot ^ ((row >> 2) & 3)) << 3);
}

// ---------------------------------------------------------------------------
// K_wprep: WfcT[c][k]=bf16(W_fc[k][c]); WgT[c][k]=bf16(W_gcn[k][c]);
//          WfT[c][k]=bf16(W_fore[k][c])
// ---------------------------------------------------------------------------
__global__ __launch_bounds__(256) void k_wprep(const float* __restrict__ W_fc,
                                               const float* __restrict__ W_gcn,
                                               const float* __restrict__ W_fore,
                                               unsigned short* __restrict__ WfcT,
                                               unsigned short* __restrict__ WgT,
                                               unsigned short* __restrict__ WfT) {
    const int i = blockIdx.x * 256 + threadIdx.x;
    if (i < 192 * 192) {
        const int c = i / 192, k = i % 192;
        WfcT[i] = f2bf(W_fc[(size_t)k * 192 + c]);
    } else if (i < 192 * 192 + 64 * 64) {
        const int j = i - 192 * 192;
        const int c = j / 64, k = j % 64;
        WgT[j] = f2bf(W_gcn[(size_t)k * 64 + c]);
    } else if (i < 192 * 192 + 64 * 64 + 256 * 64) {
        const int j = i - (192 * 192 + 64 * 64);
        const int c = j / 64, k = j % 64;
        WfT[j] = f2bf(W_fore[(size_t)k * 256 + c]);
    }
}

// ---------------------------------------------------------------------------
// K0: G -> Ag = bf16(G) row-major, BTg[n][k] = bf16(G[k][n]*(k!=n))
// ---------------------------------------------------------------------------
__global__ __launch_bounds__(256) void k_conv(const float* __restrict__ G,
                                              unsigned short* __restrict__ Ag,
                                              unsigned short* __restrict__ BTg) {
    __shared__ float T[64][65];
    const int tid = threadIdx.x;
    const int c0 = blockIdx.x * 64;
    const int r0 = blockIdx.y * 64;
    #pragma unroll
    for (int p = 0; p < 4; ++p) {
        const int g = tid + p * 256;
        const int row = g >> 4;
        const int c4 = (g & 15) * 4;
        const float4 v = *(const float4*)(G + (size_t)(r0 + row) * N_NODE + c0 + c4);
        s16x4 a;
        a[0] = (short)f2bf(v.x); a[1] = (short)f2bf(v.y);
        a[2] = (short)f2bf(v.z); a[3] = (short)f2bf(v.w);
        *(s16x4*)(Ag + (size_t)(r0 + row) * N_NODE + c0 + c4) = a;
        const int gr = r0 + row;
        T[c4 + 0][row] = (gr == c0 + c4 + 0) ? 0.f : v.x;
        T[c4 + 1][row] = (gr == c0 + c4 + 1) ? 0.f : v.y;
        T[c4 + 2][row] = (gr == c0 + c4 + 2) ? 0.f : v.z;
        T[c4 + 3][row] = (gr == c0 + c4 + 3) ? 0.f : v.w;
    }
    __syncthreads();
    #pragma unroll
    for (int p = 0; p < 4; ++p) {
        const int g = tid + p * 256;
        const int orow = g >> 4;
        const int oc4 = (g & 15) * 4;
        s16x4 o;
        o[0] = (short)f2bf(T[orow][oc4 + 0]);
        o[1] = (short)f2bf(T[orow][oc4 + 1]);
        o[2] = (short)f2bf(T[orow][oc4 + 2]);
        o[3] = (short)f2bf(T[orow][oc4 + 3]);
        *(s16x4*)(BTg + (size_t)(c0 + orow) * N_NODE + r0 + oc4) = o;
    }
}

// ---------------------------------------------------------------------------
// K1: Gsum_eff = bf16( mask*(G + G@Gm) + I/3 ).  MFMA 128x128 tile, 4 waves.
// ---------------------------------------------------------------------------
__global__ __launch_bounds__(256) void k_build(const unsigned short* __restrict__ Ag,
                                               const unsigned short* __restrict__ BTg,
                                               const float* __restrict__ G,
                                               unsigned short* __restrict__ Gsum) {
    __shared__ short Asm[128 * 32];
    __shared__ short Bsm[128 * 32];
    const int tid = threadIdx.x;
    const int n0 = blockIdx.x * 128;
    const int m0 = blockIdx.y * 128;
    const int lane = tid & 63;
    const int w = tid >> 6;
    const int wm = (w & 1) * 64;
    const int wn = (w >> 1) * 64;
    const int lr = lane & 15;
    const int lk = lane >> 4;
    const int srow = tid >> 2;
    const int sslot = tid & 3;

    f32x4 acc[4][4] = {};
    s16x8 ra0, ra1, rb0, rb1;
    ra0 = *(const s16x8*)(Ag + (size_t)(m0 + srow) * N_NODE + sslot * 8);
    ra1 = *(const s16x8*)(Ag + (size_t)(m0 + srow + 64) * N_NODE + sslot * 8);
    rb0 = *(const s16x8*)(BTg + (size_t)(n0 + srow) * N_NODE + sslot * 8);
    rb1 = *(const s16x8*)(BTg + (size_t)(n0 + srow + 64) * N_NODE + sslot * 8);

    for (int k0 = 0; k0 < N_NODE; k0 += 32) {
        __syncthreads();
        *(s16x8*)&Asm[swz_off(srow, sslot)] = ra0;
        *(s16x8*)&Asm[swz_off(srow + 64, sslot)] = ra1;
        *(s16x8*)&Bsm[swz_off(srow, sslot)] = rb0;
        *(s16x8*)&Bsm[swz_off(srow + 64, sslot)] = rb1;
        __syncthreads();
        if (k0 + 32 < N_NODE) {
            const int kn = k0 + 32;
            ra0 = *(const s16x8*)(Ag + (size_t)(m0 + srow) * N_NODE + kn + sslot * 8);
            ra1 = *(const s16x8*)(Ag + (size_t)(m0 + srow + 64) * N_NODE + kn + sslot * 8);
            rb0 = *(const s16x8*)(BTg + (size_t)(n0 + srow) * N_NODE + kn + sslot * 8);
            rb1 = *(const s16x8*)(BTg + (size_t)(n0 + srow + 64) * N_NODE + kn + sslot * 8);
        }
        s16x8 af[4], bfr[4];
        #pragma unroll
        for (int fr = 0; fr < 4; ++fr)
            af[fr] = *(const s16x8*)&Asm[swz_off(wm + fr * 16 + lr, lk)];
        #pragma unroll
        for (int fc = 0; fc < 4; ++fc)
            bfr[fc] = *(const s16x8*)&Bsm[swz_off(wn + fc * 16 + lr, lk)];
        #pragma unroll
        for (int fr = 0; fr < 4; ++fr)
            #pragma unroll
            for (int fc = 0; fc < 4; ++fc)
                acc[fr][fc] = __builtin_amdgcn_mfma_f32_16x16x32_bf16(
                    af[fr], bfr[fc], acc[fr][fc], 0, 0, 0);
    }
    #pragma unroll
    for (int fc = 0; fc < 4; ++fc) {
        const int n = n0 + wn + fc * 16 + lr;
        #pragma unroll
        for (int fr = 0; fr < 4; ++fr) {
            #pragma unroll
            for (int reg = 0; reg < 4; ++reg) {
                const int m = m0 + wm + fr * 16 + lk * 4 + reg;
                const float v = acc[fr][fc][reg] + G[(size_t)m * N_NODE + n];
                Gsum[(size_t)m * N_NODE + n] =
                    (m == n) ? f2bf(1.f / 3.f) : f2bf(v);
            }
        }
    }
}

// ---------------------------------------------------------------------------
// fc_body: per (n-tile 64, bt): h=relu(bf16(Xw)@W_fc); Xs=kt-sum; Y=Xs@W_gcn;
// write Y^T bf16 [64 d][2048 n].  F0/F1/F2 are fully offset frame pointers.
// ---------------------------------------------------------------------------
__device__ __forceinline__ void fc_body(char* smem,
                                        const float* F0, const float* F1,
                                        const float* F2,
                                        const unsigned short* WfcT,
                                        const unsigned short* WgT,
                                        unsigned short* YT,
                                        int n0, int bt_out) {
    short* As = (short*)smem;                 // [64][200] bf16  (25600 B)
    short* Bb = (short*)(smem + 25600);       // [2][192][40] bf16 (30720 B)
    float* Hs = (float*)smem;                 // [64][197] f32 (phase 2)
    short* Xs = (short*)smem;                 // [64][72] bf16 (phase 3/4)
    short* Wg = (short*)(smem + 9216);        // [64][72] bf16

    const int tid = threadIdx.x;
    const float* frames[3] = {F0, F1, F2};
    const int lane = tid & 63;
    const int w = tid >> 6;
    const int wn = w * 48;
    const int lr = lane & 15;
    const int lk = lane >> 4;

    #pragma unroll
    for (int p = 0; p < 12; ++p) {
        const int kk = p >> 2;
        const int e = tid + (p & 3) * 256;
        const int row = e >> 4;
        const int c4 = (e & 15) * 4;
        const float4 v = *(const float4*)(frames[kk] + (size_t)row * 64 + c4);
        s16x4 a;
        a[0] = (short)f2bf(v.x); a[1] = (short)f2bf(v.y);
        a[2] = (short)f2bf(v.z); a[3] = (short)f2bf(v.w);
        *(s16x4*)&As[row * 200 + kk * 64 + c4] = a;
    }
    #pragma unroll
    for (int p = 0; p < 3; ++p) {
        const int g = tid + p * 256;
        const int c = g >> 2, slot = g & 3;
        *(s16x8*)&Bb[c * 40 + slot * 8] =
            *(const s16x8*)(WfcT + (size_t)c * 192 + slot * 8);
    }
    __syncthreads();

    f32x4 acc[4][3] = {};
    for (int kc = 0; kc < 6; ++kc) {
        const int cur = kc & 1;
        s16x8 nb[3];
        if (kc < 5) {
            #pragma unroll
            for (int p = 0; p < 3; ++p) {
                const int g = tid + p * 256;
                const int c = g >> 2, slot = g & 3;
                nb[p] = *(const s16x8*)(WfcT + (size_t)c * 192 + (kc + 1) * 32 + slot * 8);
            }
        }
        s16x8 af[4], bf_[3];
        #pragma unroll
        for (int fr = 0; fr < 4; ++fr)
            af[fr] = *(const s16x8*)&As[(fr * 16 + lr) * 200 + kc * 32 + lk * 8];
        #pragma unroll
        for (int fc = 0; fc < 3; ++fc)
            bf_[fc] = *(const s16x8*)&Bb[cur * 7680 + (wn + fc * 16 + lr) * 40 + lk * 8];
        #pragma unroll
        for (int fr = 0; fr < 4; ++fr)
            #pragma unroll
            for (int fc = 0; fc < 3; ++fc)
                acc[fr][fc] = __builtin_amdgcn_mfma_f32_16x16x32_bf16(
                    af[fr], bf_[fc], acc[fr][fc], 0, 0, 0);
        if (kc < 5) {
            #pragma unroll
            for (int p = 0; p < 3; ++p) {
                const int g = tid + p * 256;
                const int c = g >> 2, slot = g & 3;
                *(s16x8*)&Bb[(cur ^ 1) * 7680 + c * 40 + slot * 8] = nb[p];
            }
        }
        __syncthreads();
    }
    #pragma unroll
    for (int fr = 0; fr < 4; ++fr)
        #pragma unroll
        for (int fc = 0; fc < 3; ++fc)
            #pragma unroll
            for (int reg = 0; reg < 4; ++reg) {
                const int row = fr * 16 + lk * 4 + reg;
                const int col = wn + fc * 16 + lr;
                Hs[row * 197 + col] = fmaxf(acc[fr][fc][reg], 0.f);
            }
    __syncthreads();
    const int xn = tid >> 2;
    const int d0 = (tid & 3) * 16;
    float xsv[16];
    #pragma unroll
    for (int q = 0; q < 16; ++q)
        xsv[q] = Hs[xn * 197 + d0 + q] + Hs[xn * 197 + 64 + d0 + q] +
                 Hs[xn * 197 + 128 + d0 + q];
    __syncthreads();
    #pragma unroll
    for (int q2 = 0; q2 < 4; ++q2) {
        s16x4 a;
        a[0] = (short)f2bf(xsv[q2 * 4 + 0]); a[1] = (short)f2bf(xsv[q2 * 4 + 1]);
        a[2] = (short)f2bf(xsv[q2 * 4 + 2]); a[3] = (short)f2bf(xsv[q2 * 4 + 3]);
        *(s16x4*)&Xs[xn * 72 + d0 + q2 * 4] = a;
    }
    #pragma unroll
    for (int p = 0; p < 2; ++p) {
        const int g = tid + p * 256;
        const int c = g >> 3, slot = g & 7;
        *(s16x8*)&Wg[c * 72 + slot * 8] = *(const s16x8*)(WgT + (size_t)c * 64 + slot * 8);
    }
    __syncthreads();
    f32x4 yac[4] = {};
    #pragma unroll
    for (int ks = 0; ks < 2; ++ks) {
        const s16x8 xa = *(const s16x8*)&Xs[(w * 16 + lr) * 72 + ks * 32 + lk * 8];
        #pragma unroll
        for (int fc = 0; fc < 4; ++fc) {
            const s16x8 wb = *(const s16x8*)&Wg[(fc * 16 + lr) * 72 + ks * 32 + lk * 8];
            yac[fc] = __builtin_amdgcn_mfma_f32_16x16x32_bf16(xa, wb, yac[fc], 0, 0, 0);
        }
    }
    #pragma unroll
    for (int fc = 0; fc < 4; ++fc) {
        const int d = fc * 16 + lr;
        s16x4 o;
        o[0] = (short)f2bf(yac[fc][0]); o[1] = (short)f2bf(yac[fc][1]);
        o[2] = (short)f2bf(yac[fc][2]); o[3] = (short)f2bf(yac[fc][3]);
        *(s16x4*)(YT + ((size_t)bt_out * 64 + d) * N_NODE + n0 + w * 16 + lk * 4) = o;
    }
}

// ---------------------------------------------------------------------------
// prop_body: out[bt] = Gsum_eff @ Y[bt] (+ b_gcn).  128 rows x 2 bt.
// ---------------------------------------------------------------------------
__device__ __forceinline__ void prop_body(char* smem,
                                          const unsigned short* Gsum,
                                          const unsigned short* YT,
                                          const float* b_gcn,
                                          float* out_base, long long bt_stride,
                                          float* p0_base,
                                          int m0, int bt0, int kbeg, int kend,
                                          bool use_atomic, bool bias_on) {
    short* Asm = (short*)smem;             // 128*32 bf16 (8192 B)
    short* Bsm = (short*)(smem + 8192);    // 128*32 bf16
    const int tid = threadIdx.x;
    const int lane = tid & 63;
    const int w = tid >> 6;
    const int wm = (w & 1) * 64;
    const int wn = (w >> 1) * 64;
    const int lr = lane & 15;
    const int lk = lane >> 4;
    const int srow = tid >> 2;
    const int sslot = tid & 3;
    const unsigned short* Yb0 = YT + (size_t)bt0 * 64 * N_NODE;
    const unsigned short* Yb1 = YT + (size_t)(bt0 + 1) * 64 * N_NODE;

    f32x4 acc[4][4] = {};
    s16x8 ra0, ra1, rb0, rb1;
    ra0 = *(const s16x8*)(Gsum + (size_t)(m0 + srow) * N_NODE + kbeg + sslot * 8);
    ra1 = *(const s16x8*)(Gsum + (size_t)(m0 + srow + 64) * N_NODE + kbeg + sslot * 8);
    rb0 = *(const s16x8*)(Yb0 + (size_t)srow * N_NODE + kbeg + sslot * 8);
    rb1 = *(const s16x8*)(Yb1 + (size_t)srow * N_NODE + kbeg + sslot * 8);

    for (int k0 = kbeg; k0 < kend; k0 += 32) {
        __syncthreads();
        *(s16x8*)&Asm[swz_off(srow, sslot)] = ra0;
        *(s16x8*)&Asm[swz_off(srow + 64, sslot)] = ra1;
        *(s16x8*)&Bsm[swz_off(srow, sslot)] = rb0;
        *(s16x8*)&Bsm[swz_off(srow + 64, sslot)] = rb1;
        __syncthreads();
        if (k0 + 32 < kend) {
            const int kn = k0 + 32;
            ra0 = *(const s16x8*)(Gsum + (size_t)(m0 + srow) * N_NODE + kn + sslot * 8);
            ra1 = *(const s16x8*)(Gsum + (size_t)(m0 + srow + 64) * N_NODE + kn + sslot * 8);
            rb0 = *(const s16x8*)(Yb0 + (size_t)srow * N_NODE + kn + sslot * 8);
            rb1 = *(const s16x8*)(Yb1 + (size_t)srow * N_NODE + kn + sslot * 8);
        }
        s16x8 af[4], bfr[4];
        #pragma unroll
        for (int fr = 0; fr < 4; ++fr)
            af[fr] = *(const s16x8*)&Asm[swz_off(wm + fr * 16 + lr, lk)];
        #pragma unroll
        for (int fc = 0; fc < 4; ++fc)
            bfr[fc] = *(const s16x8*)&Bsm[swz_off(wn + fc * 16 + lr, lk)];
        #pragma unroll
        for (int fr = 0; fr < 4; ++fr)
            #pragma unroll
            for (int fc = 0; fc < 4; ++fc)
                acc[fr][fc] = __builtin_amdgcn_mfma_f32_16x16x32_bf16(
                    af[fr], bfr[fc], acc[fr][fc], 0, 0, 0);
    }
    #pragma unroll
    for (int fc = 0; fc < 4; ++fc) {
        const int col = wn + fc * 16 + lr;
        const int btg = bt0 + (col >> 6);
        const int d = col & 63;
        const float bias = bias_on ? b_gcn[d] : 0.f;
        float* op = out_base + (size_t)btg * (size_t)bt_stride;
        float* pp = nullptr;
        if (!use_atomic && p0_base != nullptr && (btg % 10) == 9)
            pp = p0_base + (size_t)(btg / 10) * ((size_t)L_SEQ * ND);
        #pragma unroll
        for (int frr = 0; frr < 4; ++frr) {
            const int mb = m0 + wm + frr * 16 + lk * 4;
            #pragma unroll
            for (int reg = 0; reg < 4; ++reg) {
                const size_t off = (size_t)(mb + reg) * D_DIM + d;
                const float v = acc[frr][fc][reg] + bias;
                if (!use_atomic) {
                    op[off] = v;
                    if (pp) pp[off] = v;
                } else {
                    atomicAdd(op + off, v);
                }
            }
        }
    }
}

// ---------------------------------------------------------------------------
// Stage-B wrappers
// ---------------------------------------------------------------------------
__global__ __launch_bounds__(256) void k_fc(const float* __restrict__ f0,
                                            const float* __restrict__ f1,
                                            const float* __restrict__ f2,
                                            const unsigned short* __restrict__ WfcT,
                                            const unsigned short* __restrict__ WgT,
                                            unsigned short* __restrict__ YT,
                                            int t_count) {
    __shared__ __align__(16) char smem[56320];
    const int n0 = blockIdx.x * 64;
    const int bt = blockIdx.y;
    const int b = bt / t_count, t = bt % t_count;
    const size_t base = (size_t)b * L_SEQ * ND + (size_t)t * ND + (size_t)n0 * D_DIM;
    fc_body(smem, f0 + base, f1 + base, f2 + base, WfcT, WgT, YT, n0, bt);
}

// fc (t_count=1) + fused zeroing of one P frame across all 4 batches
// (Pz = P + i*ND; zero target = Pz + b2*L_SEQ*ND + off). grid = (32, 4).
__global__ __launch_bounds__(256) void k_fcz(const float* __restrict__ f0,
                                             const float* __restrict__ f1,
                                             const float* __restrict__ f2,
                                             const unsigned short* __restrict__ WfcT,
                                             const unsigned short* __restrict__ WgT,
                                             unsigned short* __restrict__ YT,
                                             float* __restrict__ Pz) {
    __shared__ __align__(16) char smem[56320];
    const int n0 = blockIdx.x * 64;
    const int b = blockIdx.y;
    const int fid = blockIdx.y * 32 + blockIdx.x;   // 0..127
    // zero share first (independent of fc work)
    {
        const float4 z4 = {0.f, 0.f, 0.f, 0.f};
        #pragma unroll
        for (int p = 0; p < 4; ++p) {
            const size_t g = ((size_t)(fid * 256 + threadIdx.x) + (size_t)p * 32768) * 4;
            const size_t b2 = g / ND;
            const size_t off = g - b2 * ND;
            *(float4*)(Pz + b2 * L_SEQ * ND + off) = z4;
        }
    }
    const size_t base = (size_t)b * L_SEQ * ND + (size_t)n0 * D_DIM;
    fc_body(smem, f0 + base, f1 + base, f2 + base, WfcT, WgT, YT, n0, b);
}

__global__ __launch_bounds__(256) void k_prop(const unsigned short* __restrict__ Gsum,
                                              const unsigned short* __restrict__ YT,
                                              const float* __restrict__ b_gcn,
                                              float* __restrict__ out_base,
                                              long long bt_stride,
                                              float* __restrict__ p0_base) {
    __shared__ __align__(16) char smem[16384];
    prop_body(smem, Gsum, YT, b_gcn, out_base, bt_stride, p0_base,
              blockIdx.x * 128, blockIdx.y * 2, 0, N_NODE, false, true);
}

// split-K=4 atomic prop; grid = (16, 2, 4)
__global__ __launch_bounds__(256) void k_prop4(const unsigned short* __restrict__ Gsum,
                                               const unsigned short* __restrict__ YT,
                                               const float* __restrict__ b_gcn,
                                               float* __restrict__ out_base,
                                               long long bt_stride) {
    __shared__ __align__(16) char smem[16384];
    const int kz = blockIdx.z;
    prop_body(smem, Gsum, YT, b_gcn, out_base, bt_stride, nullptr,
              blockIdx.x * 128, blockIdx.y * 2, kz * 512, kz * 512 + 512,
              true, kz == 0);
}

// ---------------------------------------------------------------------------
// K_chain: the whole 11-step autoregressive loop, one cooperative kernel.
// ---------------------------------------------------------------------------
__global__ __launch_bounds__(256) void k_chain(const unsigned short* __restrict__ Gsum,
                                               const float* __restrict__ X_spa,
                                               float* __restrict__ P,
                                               const unsigned short* __restrict__ WfcT,
                                               const unsigned short* __restrict__ WgT,
                                               unsigned short* __restrict__ YTs,
                                               const float* __restrict__ b_gcn) {
    __shared__ __align__(16) char smem[56320];
    cg::grid_group grid = cg::this_grid();
    const int bid = blockIdx.x;
    const int tid = threadIdx.x;

    for (int i = 1; i <= 11; ++i) {
        const float *f0, *f1, *f2;
        if (i == 1)      { f0 = X_spa + 10 * ND; f1 = X_spa + 11 * ND; f2 = P; }
        else if (i == 2) { f0 = X_spa + 11 * ND; f1 = P;               f2 = P + ND; }
        else             { f0 = P + (size_t)(i - 3) * ND;
                           f1 = P + (size_t)(i - 2) * ND;
                           f2 = P + (size_t)(i - 1) * ND; }
        // phase A: fc for 4 bt
        {
            const int n0 = (bid & 31) * 64;
            const int b = bid >> 5;
            const size_t base = (size_t)b * L_SEQ * ND + (size_t)n0 * D_DIM;
            fc_body(smem, f0 + base, f1 + base, f2 + base, WfcT, WgT, YTs, n0, b);
        }
        // zero P frame i (all 4 batches) for the split-K atomics
        {
            const float4 z4 = {0.f, 0.f, 0.f, 0.f};
            #pragma unroll
            for (int p = 0; p < 4; ++p) {
                const size_t g = ((size_t)(bid * 256 + tid) + (size_t)p * 32768) * 4;
                const size_t b = g / ND;
                const size_t off = g - b * ND;
                *(float4*)(P + b * L_SEQ * ND + (size_t)i * ND + off) = z4;
            }
        }
        __threadfence();
        grid.sync();
        // phase B: prop split-K4 with atomics
        {
            const int m0 = (bid & 15) * 128;
            const int bty = (bid >> 4) & 1;
            const int kz = bid >> 5;
            prop_body(smem, Gsum, YTs, b_gcn, P + (size_t)i * ND,
                      (long long)(L_SEQ * ND), nullptr,
                      m0, bty * 2, kz * 512, kz * 512 + 512, true, kz == 0);
        }
        __threadfence();
        grid.sync();
    }
}

// ---------------------------------------------------------------------------
// K4: forecast = P @ W_fore + b_fore.  MFMA, swapped operands.
// ---------------------------------------------------------------------------
__global__ __launch_bounds__(256) void k_forecast(const float* __restrict__ P,
                                                  const unsigned short* __restrict__ WfT,
                                                  const float* __restrict__ b_fore,
                                                  float* __restrict__ out) {
    __shared__ short Wl[256 * 72];   // 36 KB, pad 64->72
    __shared__ short Al[64 * 72];    //  9 KB
    const int tid = threadIdx.x;
    const int lane = tid & 63;
    const int w = tid >> 6;          // wave w -> output cols w*64..w*64+63
    const int lr = lane & 15;
    const int lk = lane >> 4;
    const size_t row0 = (size_t)blockIdx.x * 64;

    #pragma unroll
    for (int p = 0; p < 8; ++p) {
        const int g = tid + p * 256;
        const int c = g >> 3, slot = g & 7;
        *(s16x8*)&Wl[c * 72 + slot * 8] = *(const s16x8*)(WfT + (size_t)c * 64 + slot * 8);
    }
    #pragma unroll
    for (int p = 0; p < 4; ++p) {
        const int g = tid + p * 256;
        const int r = g >> 4;
        const int c4 = (g & 15) * 4;
        const float4 v = *(const float4*)(P + (row0 + r) * D_DIM + c4);
        s16x4 a;
        a[0] = (short)f2bf(v.x); a[1] = (short)f2bf(v.y);
        a[2] = (short)f2bf(v.z); a[3] = (short)f2bf(v.w);
        *(s16x4*)&Al[r * 72 + c4] = a;
    }
    __syncthreads();

    f32x4 acc[4][4] = {};   // [fc: col frag][fr: row frag]
    #pragma unroll
    for (int ks = 0; ks < 2; ++ks) {
        s16x8 wf[4], pf[4];
        #pragma unroll
        for (int fc = 0; fc < 4; ++fc)
            wf[fc] = *(const s16x8*)&Wl[(w * 64 + fc * 16 + lr) * 72 + ks * 32 + lk * 8];
        #pragma unroll
        for (int fr = 0; fr < 4; ++fr)
            pf[fr] = *(const s16x8*)&Al[(fr * 16 + lr) * 72 + ks * 32 + lk * 8];
        #pragma unroll
        for (int fc = 0; fc < 4; ++fc)
            #pragma unroll
            for (int fr = 0; fr < 4; ++fr)
                acc[fc][fr] = __builtin_amdgcn_mfma_f32_16x16x32_bf16(
                    wf[fc], pf[fr], acc[fc][fr], 0, 0, 0);
    }
    #pragma unroll
    for (int fc = 0; fc < 4; ++fc) {
        const int c0 = w * 64 + fc * 16 + lk * 4;
        const float4 bb = *(const float4*)(b_fore + c0);
        #pragma unroll
        for (int fr = 0; fr < 4; ++fr) {
            const int r = fr * 16 + lr;
            float4 o;
            o.x = acc[fc][fr][0] + bb.x;
            o.y = acc[fc][fr][1] + bb.y;
            o.z = acc[fc][fr][2] + bb.z;
            o.w = acc[fc][fr][3] + bb.w;
            *(float4*)(out + (row0 + r) * 256 + c0) = o;
        }
    }
}

// ---------------------------------------------------------------------------
// K5: backcast = LN(X[:,2:] - relu(Z @ W_back + b_back)).
// ---------------------------------------------------------------------------
__global__ __launch_bounds__(256) void k_backcast(const float* __restrict__ Z,
                                                  const float* __restrict__ X,
                                                  const float* __restrict__ W_back,
                                                  const float* __restrict__ b_back,
                                                  const float* __restrict__ gamma,
                                                  const float* __restrict__ beta,
                                                  float* __restrict__ out) {
    const int tid = threadIdx.x;
    const int lane = tid & 63;
    const int wid = tid >> 6;
    const size_t row = (size_t)blockIdx.x * 4 + wid;
    const int bt = (int)(row >> 11);
    const int b = bt / 10;
    const int t = bt % 10;
    const size_t n = row & 2047;
    const float z = Z[row * D_DIM + lane];
    float back = b_back[lane];
    #pragma unroll 8
    for (int k = 0; k < 64; ++k) {
        const float zk = __shfl(z, k, 64);
        back = fmaf(zk, W_back[k * D_DIM + lane], back);
    }
    const float xr = X[(((size_t)b * L_SEQ + t + 2) * N_NODE + n) * D_DIM + lane];
    const float u = xr - fmaxf(back, 0.f);
    float s = u;
    #pragma unroll
    for (int off = 32; off > 0; off >>= 1) s += __shfl_xor(s, off, 64);
    const float mu = s * (1.f / 64.f);
    const float dv = u - mu;
    float s2 = dv * dv;
    #pragma unroll
    for (int off = 32; off > 0; off >>= 1) s2 += __shfl_xor(s2, off, 64);
    const float var = s2 * (1.f / 64.f);
    out[row * D_DIM + lane] = dv * rsqrtf(var + 1e-5f) * gamma[lane] + beta[lane];
}

// ---------------------------------------------------------------------------
extern "C" void kernel_launch(void* const* d_in, const int* in_sizes, int n_in,
                              void* d_out, int out_size, void* d_ws, size_t ws_size,
                              hipStream_t stream) {
    (void)in_sizes; (void)n_in; (void)out_size; (void)ws_size;
    const float* X      = (const float*)d_in[0];
    const float* X_spa  = (const float*)d_in[1];
    const float* G      = (const float*)d_in[2];
    const float* W_fc   = (const float*)d_in[3];
    const float* W_gcn  = (const float*)d_in[4];
    const float* b_gcn  = (const float*)d_in[5];
    const float* W_fore = (const float*)d_in[6];
    const float* b_fore = (const float*)d_in[7];
    const float* W_back = (const float*)d_in[8];
    const float* b_back = (const float*)d_in[9];
    const float* gamma  = (const float*)d_in[10];
    const float* beta   = (const float*)d_in[11];

    float* backcast = (float*)d_out;                      // 4*10*2048*64
    float* forecast = (float*)d_out + (size_t)5242880;    // 4*12*2048*256

    // workspace layout (80 MB), every byte written before read
    char* wsb = (char*)d_ws;
    unsigned short* Gsum = (unsigned short*)wsb;                        //  0.. 8 MB
    unsigned short* Ag   = (unsigned short*)(wsb + ((size_t)8 << 20));  //  8..16
    unsigned short* BTg  = (unsigned short*)(wsb + ((size_t)16 << 20)); // 16..24
    unsigned short* YTb  = (unsigned short*)(wsb + ((size_t)24 << 20)); // 24..34
    unsigned short* YTs  = (unsigned short*)(wsb + ((size_t)34 << 20)); // 34..35
    unsigned short* WfcT = (unsigned short*)(wsb + ((size_t)35 << 20)); // 72 KB
    unsigned short* WgT  = WfcT + 192 * 192;                            //  8 KB
    unsigned short* WfT  = WgT + 64 * 64;                               // 32 KB
    float* Z             = (float*)(wsb + ((size_t)36 << 20));          // 36..56
    float* P             = (float*)(wsb + ((size_t)56 << 20));          // 56..80

    const dim3 blk(256);

    k_wprep<<<dim3(224), blk, 0, stream>>>(W_fc, W_gcn, W_fore, WfcT, WgT, WfT);
    k_conv<<<dim3(32, 32), blk, 0, stream>>>(G, Ag, BTg);
    k_build<<<dim3(16, 16), blk, 0, stream>>>(Ag, BTg, G, Gsum);

    // Stage B: t=0..9 over 4 batches (40 bt)
    k_fc<<<dim3(32, 40), blk, 0, stream>>>(X_spa, X_spa + ND, X_spa + 2 * ND,
                                           WfcT, WgT, YTb, 10);
    k_prop<<<dim3(16, 20), blk, 0, stream>>>(Gsum, YTb, b_gcn,
                                             Z, (long long)ND, P);

    // Stage C: try the fused cooperative chain; on ANY launch failure, fall
    // back to the proven per-step launches (identical math).
    hipError_t ce;
    {
        const unsigned short* aGsum = Gsum;
        const float* aXspa = X_spa;
        float* aP = P;
        const unsigned short* aWfcT = WfcT;
        const unsigned short* aWgT = WgT;
        unsigned short* aYTs = YTs;
        const float* aBg = b_gcn;
        void* args[] = {(void*)&aGsum, (void*)&aXspa, (void*)&aP,
                        (void*)&aWfcT, (void*)&aWgT, (void*)&aYTs, (void*)&aBg};
        ce = hipLaunchCooperativeKernel((const void*)k_chain, dim3(128), blk,
                                        args, 0, stream);
    }
    if (ce != hipSuccess) {
        (void)hipGetLastError();   // clear sticky error from the failed launch
        for (int i = 1; i <= 11; ++i) {
            const float *f0, *f1, *f2;
            if (i == 1)      { f0 = X_spa + 10 * ND; f1 = X_spa + 11 * ND; f2 = P; }
            else if (i == 2) { f0 = X_spa + 11 * ND; f1 = P;               f2 = P + ND; }
            else             { f0 = P + (size_t)(i - 3) * ND;
                               f1 = P + (size_t)(i - 2) * ND;
                               f2 = P + (size_t)(i - 1) * ND; }
            k_fcz<<<dim3(32, 4), blk, 0, stream>>>(f0, f1, f2, WfcT, WgT, YTs,
                                                   P + (size_t)i * ND);
            k_prop4<<<dim3(16, 2, 4), blk, 0, stream>>>(Gsum, YTs, b_gcn,
                                                        P + (size_t)i * ND,
                                                        (long long)(L_SEQ * ND));
        }
    }

    k_forecast<<<dim3(1536), blk, 0, stream>>>(P, WfT, b_fore, forecast);
    k_backcast<<<dim3(20480), blk, 0, stream>>>(Z, X, W_back, b_back,
                                                gamma, beta, backcast);
}